// Round 6
// baseline (364.205 us; speedup 1.0000x reference)
//
#include <hip/hip_runtime.h>

typedef unsigned short u16;
typedef unsigned int u32;
typedef __bf16 bf16;
typedef __attribute__((ext_vector_type(8))) bf16 bf16x8;
typedef __attribute__((ext_vector_type(16))) float f32x16;
typedef __attribute__((ext_vector_type(8))) u16 u16x8;

#define M_DIM 8192
#define N_DIM 4096
#define K_DIM 4096
#define NTK   (K_DIM / 64)   // 64 K-tiles of 64

__device__ __forceinline__ u16 f2bf(float f) {
    u32 u = __float_as_uint(f);
    u32 r = (u + 0x7fffu + ((u >> 16) & 1u)) >> 16;
    return (u16)r;
}

__device__ __forceinline__ float softplus_f(float x) {
    return fmaxf(x, 0.f) + log1pf(expf(-fabsf(x)));
}

__device__ __forceinline__ void gload_lds16(const void* g, void* l) {
    __builtin_amdgcn_global_load_lds(
        (const __attribute__((address_space(1))) void*)g,
        (__attribute__((address_space(3))) void*)l,
        16, 0, 0);
}

// ---------------- x -> bf16 cast ----------------
__global__ void conv_x_kernel(const float* __restrict__ x, u16* __restrict__ xb,
                              long long n8) {
    long long idx = blockIdx.x * (long long)blockDim.x + threadIdx.x;
    long long stride = gridDim.x * (long long)blockDim.x;
    for (long long i = idx; i < n8; i += stride) {
        const float4* xp = (const float4*)(x + i * 8);
        float4 a = xp[0], b = xp[1];
        u16x8 r;
        r[0] = f2bf(a.x); r[1] = f2bf(a.y); r[2] = f2bf(a.z); r[3] = f2bf(a.w);
        r[4] = f2bf(b.x); r[5] = f2bf(b.y); r[6] = f2bf(b.z); r[7] = f2bf(b.w);
        *(u16x8*)(xb + i * 8) = r;
    }
}

// ------- W sample + transpose: Wt[n][k] = bf16(w_loc + softplus(w_std)*eps_w) -------
__global__ void wconv_kernel(const float* __restrict__ w_loc,
                             const float* __restrict__ w_std,
                             const float* __restrict__ eps_w,
                             u16* __restrict__ wt) {
    __shared__ u16 t[64][66];
    const int kb = blockIdx.x & 63;
    const int nb = blockIdx.x >> 6;
    const int k0 = kb * 64, n0 = nb * 64;
    const int tx = threadIdx.x & 63;
    const int ty = threadIdx.x >> 6;
#pragma unroll
    for (int r = 0; r < 64; r += 4) {
        const size_t off = (size_t)(k0 + r + ty) * N_DIM + n0 + tx;
        float v = w_loc[off] + softplus_f(w_std[off]) * eps_w[off];
        t[r + ty][tx] = f2bf(v);
    }
    __syncthreads();
#pragma unroll
    for (int r = 0; r < 64; r += 4) {
        wt[(size_t)(n0 + r + ty) * K_DIM + k0 + tx] = t[tx][r + ty];
    }
}

// ---------------- bias ----------------
__global__ void bias_kernel(const float* __restrict__ b_loc,
                            const float* __restrict__ b_std,
                            const float* __restrict__ eps_b,
                            float* __restrict__ bias) {
    int i = blockIdx.x * blockDim.x + threadIdx.x;
    if (i < N_DIM) bias[i] = b_loc[i] + softplus_f(b_std[i]) * eps_b[i];
}

// ---------------- 256x256 4-phase/K-tile bf16 GEMM, 32x32x16 MFMA ----------------
// C[M][N] = Xb[M][K] @ Wt[N][K]^T + bias. BK=64, 8 waves (2Mx4N), 128 KiB LDS.
// Per-wave 128x64 out = 4 m-blocks x 2 n-blocks of 32x32; acc[4][2] f32x16.
// RACE DISCIPLINE (round-5 lesson): stageB(u+2) writes the SAME buffer parity
// as the B(u) being consumed. Therefore ALL B(u) reads are issued in phase 0
// and complete before phase 0's closing barrier (each wave does lgkmcnt(0)
// before arriving) -> stageB at phases 2/3 is write-after-read safe.
// stageA(u+1) writes the opposite parity -> always safe.
// Per tile u, phase ks: { 4 A ds_read_b128 (ph0: +8 B reads) | stage one
// half-tile (2 gload_lds) | barrier | lgkmcnt(0) | setprio(1) | 8 MFMA |
// setprio(0) | (ph3: counted vmcnt(4)) | barrier }. vmcnt(4) leaves exactly
// B(u+2) in flight; never drains to 0 mid-loop.
// Swizzle (128B rows): 16B-granule g = (ks*2+hi2) ^ (row&7); DMA source
// pre-swizzled q = (tid&7)^((tid>>3)&7), linear dest (rule #21).
__global__ __launch_bounds__(512, 2) void gemm_kernel(
    const u16* __restrict__ Xb, const u16* __restrict__ Wt,
    const float* __restrict__ bias, float* __restrict__ C) {
    extern __shared__ u16 lds[];   // 128 KiB: A [2][256][64] at 0, B at 32768

    const int tid = threadIdx.x;
    const int l  = tid & 63;
    const int w  = tid >> 6;          // wave 0..7
    const int wm = w >> 2;            // 0..1
    const int wn = w & 3;             // 0..3

    // T1: XCD-bijective swizzle (512 blocks, 512 % 8 == 0)
    const int swz = (blockIdx.x & 7) * 64 + (blockIdx.x >> 3);
    const int m0 = (swz >> 4) * 256;  // 32 M-tiles
    const int n0 = (swz & 15) * 256;  // 16 N-tiles

    const u16* Ab = Xb + (size_t)m0 * K_DIM;
    const u16* Bb = Wt + (size_t)n0 * K_DIM;

    // staging: srow = tid>>3 (0..63), granule tid&7 (linear dest)
    const int srow = tid >> 3;
    const int sq   = ((tid & 7) ^ (srow & 7)) * 8;    // pre-swizzled col elems

    // read lane decomposition for 32x32 fragments
    const int lane31 = l & 31;
    const int hi2    = l >> 5;        // k-granule half
    const int rsw    = l & 7;         // row&7 for all LDS rows we touch

    auto stageA = [&](int u, int h) {
#pragma unroll
        for (int s = 0; s < 2; ++s) {
            const u16* g = Ab + (size_t)(h * 128 + s * 64 + srow) * K_DIM + u * 64 + sq;
            gload_lds16(g, &lds[(u & 1) * 16384 + h * 8192 + s * 4096 + tid * 8]);
        }
    };
    auto stageB = [&](int u, int h) {
#pragma unroll
        for (int s = 0; s < 2; ++s) {
            const u16* g = Bb + (size_t)(h * 128 + s * 64 + srow) * K_DIM + u * 64 + sq;
            gload_lds16(g, &lds[32768 + (u & 1) * 16384 + h * 8192 + s * 4096 + tid * 8]);
        }
    };

    f32x16 acc[4][2] = {};

    // ---- prologue: A(0), B(0), B(1) in flight; wait A(0),B(0) ----
    stageA(0, 0); stageA(0, 1); stageB(0, 0); stageB(0, 1);
    stageB(1, 0); stageB(1, 1);
    asm volatile("s_waitcnt vmcnt(4)" ::: "memory");
    __builtin_amdgcn_sched_barrier(0);
    __builtin_amdgcn_s_barrier();

#define CE(KS) ((((KS) * 2 + hi2) ^ rsw) << 3)

#define PHASE(KS, STAGE_STMT, DRAIN_STMT)                                     \
        {                                                                     \
            if ((KS) > 0) {                                                   \
                _Pragma("unroll")                                             \
                for (int mb = 0; mb < 4; ++mb)                                \
                    a[mb] = *(const bf16x8*)&lds[abase + mb * 2048 + CE(KS)]; \
            }                                                                 \
            STAGE_STMT;                                                       \
            __builtin_amdgcn_s_barrier();                                     \
            asm volatile("s_waitcnt lgkmcnt(0)" ::: "memory");                \
            __builtin_amdgcn_sched_barrier(0);                                \
            __builtin_amdgcn_s_setprio(1);                                    \
            _Pragma("unroll")                                                 \
            for (int mb = 0; mb < 4; ++mb) {                                  \
                acc[mb][0] = __builtin_amdgcn_mfma_f32_32x32x16_bf16(         \
                    a[mb], b[KS][0], acc[mb][0], 0, 0, 0);                    \
                acc[mb][1] = __builtin_amdgcn_mfma_f32_32x32x16_bf16(         \
                    a[mb], b[KS][1], acc[mb][1], 0, 0, 0);                    \
            }                                                                 \
            __builtin_amdgcn_s_setprio(0);                                    \
            DRAIN_STMT;                                                       \
            __builtin_amdgcn_sched_barrier(0);                                \
            __builtin_amdgcn_s_barrier();                                     \
        }

    for (int u = 0; u < NTK; ++u) {
        const int abase = (u & 1) * 16384 + (wm * 128 + lane31) * 64;
        const int bbase = 32768 + (u & 1) * 16384 + (wn * 64 + lane31) * 64;

        bf16x8 a[4], b[4][2];
        // front-load ALL B(u) reads (race discipline, see header comment)
#pragma unroll
        for (int ks = 0; ks < 4; ++ks) {
            b[ks][0] = *(const bf16x8*)&lds[bbase + CE(ks)];
            b[ks][1] = *(const bf16x8*)&lds[bbase + 2048 + CE(ks)];
        }
#pragma unroll
        for (int mb = 0; mb < 4; ++mb)
            a[mb] = *(const bf16x8*)&lds[abase + mb * 2048 + CE(0)];

        PHASE(0, { if (u + 1 < NTK) stageA(u + 1, 0); }, {});
        PHASE(1, { if (u + 1 < NTK) stageA(u + 1, 1); }, {});
        PHASE(2, { if (u + 2 < NTK) stageB(u + 2, 0); }, {});
        PHASE(3, { if (u + 2 < NTK) stageB(u + 2, 1); },
              {
                  if (u + 2 < NTK) {
                      asm volatile("s_waitcnt vmcnt(4)" ::: "memory");
                  } else if (u + 1 < NTK) {
                      asm volatile("s_waitcnt vmcnt(0)" ::: "memory");
                  }
              });
    }
#undef PHASE
#undef CE

    // ---- epilogue: C/D layout col=lane&31, row=(r&3)+8*(r>>2)+4*hi2 ----
    const int orow0 = m0 + wm * 128;
    const int ocol0 = n0 + wn * 64;
    float bv[2];
    bv[0] = bias[ocol0 + lane31];
    bv[1] = bias[ocol0 + 32 + lane31];
#pragma unroll
    for (int mb = 0; mb < 4; ++mb)
#pragma unroll
        for (int nb = 0; nb < 2; ++nb)
#pragma unroll
            for (int r = 0; r < 16; ++r) {
                const int row = orow0 + mb * 32 + (r & 3) + 8 * (r >> 2) + 4 * hi2;
                const int col = ocol0 + nb * 32 + lane31;
                C[(size_t)row * N_DIM + col] = acc[mb][nb][r] + bv[nb];
            }
}

extern "C" void kernel_launch(void* const* d_in, const int* in_sizes, int n_in,
                              void* d_out, int out_size, void* d_ws, size_t ws_size,
                              hipStream_t stream) {
    const float* x     = (const float*)d_in[0];
    const float* w_loc = (const float*)d_in[1];
    const float* w_std = (const float*)d_in[2];
    const float* b_loc = (const float*)d_in[3];
    const float* b_std = (const float*)d_in[4];
    const float* eps_w = (const float*)d_in[5];
    const float* eps_b = (const float*)d_in[6];
    float* out = (float*)d_out;

    char* ws = (char*)d_ws;
    u16* Xb   = (u16*)ws;                                            // 64 MB
    u16* Wt   = (u16*)(ws + (size_t)M_DIM * K_DIM * 2);              // 32 MB
    float* bv = (float*)(ws + (size_t)M_DIM * K_DIM * 2
                            + (size_t)N_DIM * K_DIM * 2);            // 16 KB

    (void)hipFuncSetAttribute((const void*)gemm_kernel,
                              hipFuncAttributeMaxDynamicSharedMemorySize, 131072);

    conv_x_kernel<<<2048, 256, 0, stream>>>(x, Xb, (long long)M_DIM * K_DIM / 8);
    wconv_kernel<<<(K_DIM / 64) * (N_DIM / 64), 256, 0, stream>>>(w_loc, w_std, eps_w, Wt);
    bias_kernel<<<N_DIM / 256, 256, 0, stream>>>(b_loc, b_std, eps_b, bv);
    gemm_kernel<<<(M_DIM / 256) * (N_DIM / 256), 512, 131072, stream>>>(Xb, Wt, bv, out);
}

// Round 7
// 326.247 us; speedup vs baseline: 1.1163x; 1.1163x over previous
//
#include <hip/hip_runtime.h>

typedef unsigned short u16;
typedef unsigned int u32;
typedef __bf16 bf16;
typedef __attribute__((ext_vector_type(8))) bf16 bf16x8;
typedef __attribute__((ext_vector_type(4))) float f32x4;
typedef __attribute__((ext_vector_type(8))) u16 u16x8;

#define M_DIM 8192
#define N_DIM 4096
#define K_DIM 4096
#define NTK   (K_DIM / 64)   // 64 K-tiles of 64

__device__ __forceinline__ u16 f2bf(float f) {
    u32 u = __float_as_uint(f);
    u32 r = (u + 0x7fffu + ((u >> 16) & 1u)) >> 16;
    return (u16)r;
}

__device__ __forceinline__ float softplus_f(float x) {
    return fmaxf(x, 0.f) + log1pf(expf(-fabsf(x)));
}

__device__ __forceinline__ void gload_lds16(const void* g, void* l) {
    __builtin_amdgcn_global_load_lds(
        (const __attribute__((address_space(1))) void*)g,
        (__attribute__((address_space(3))) void*)l,
        16, 0, 0);
}

// ---------------- x -> bf16 cast ----------------
__global__ void conv_x_kernel(const float* __restrict__ x, u16* __restrict__ xb,
                              long long n8) {
    long long idx = blockIdx.x * (long long)blockDim.x + threadIdx.x;
    long long stride = gridDim.x * (long long)blockDim.x;
    for (long long i = idx; i < n8; i += stride) {
        const float4* xp = (const float4*)(x + i * 8);
        float4 a = xp[0], b = xp[1];
        u16x8 r;
        r[0] = f2bf(a.x); r[1] = f2bf(a.y); r[2] = f2bf(a.z); r[3] = f2bf(a.w);
        r[4] = f2bf(b.x); r[5] = f2bf(b.y); r[6] = f2bf(b.z); r[7] = f2bf(b.w);
        *(u16x8*)(xb + i * 8) = r;
    }
}

// ------- W sample + transpose: Wt[n][k] = bf16(w_loc + softplus(w_std)*eps_w) -------
__global__ void wconv_kernel(const float* __restrict__ w_loc,
                             const float* __restrict__ w_std,
                             const float* __restrict__ eps_w,
                             u16* __restrict__ wt) {
    __shared__ u16 t[64][66];
    const int kb = blockIdx.x & 63;
    const int nb = blockIdx.x >> 6;
    const int k0 = kb * 64, n0 = nb * 64;
    const int tx = threadIdx.x & 63;
    const int ty = threadIdx.x >> 6;
#pragma unroll
    for (int r = 0; r < 64; r += 4) {
        const size_t off = (size_t)(k0 + r + ty) * N_DIM + n0 + tx;
        float v = w_loc[off] + softplus_f(w_std[off]) * eps_w[off];
        t[r + ty][tx] = f2bf(v);
    }
    __syncthreads();
#pragma unroll
    for (int r = 0; r < 64; r += 4) {
        wt[(size_t)(n0 + r + ty) * K_DIM + k0 + tx] = t[tx][r + ty];
    }
}

// ---------------- bias ----------------
__global__ void bias_kernel(const float* __restrict__ b_loc,
                            const float* __restrict__ b_std,
                            const float* __restrict__ eps_b,
                            float* __restrict__ bias) {
    int i = blockIdx.x * blockDim.x + threadIdx.x;
    if (i < N_DIM) bias[i] = b_loc[i] + softplus_f(b_std[i]) * eps_b[i];
}

// ------- 256x256 bf16 GEMM, 1 barrier/tile, counted lgkm/vmcnt flow -------
// C[M][N] = Xb[M][K] @ Wt[N][K]^T + bias. BK=64, 8 waves (2Mx4N), 160 KiB LDS:
// A double-buffered [2][256][64] @0, B TRIPLE-buffered [3][256][64] @32768.
// Per tile u: {12 ds_read | stageA(u+1) | lgkm(0) | 32 MFMA}ks0
//             {12 ds_read | stageB(u+2)->slot (u+2)%3 | lgkm(0) | 32 MFMA}ks1
//             vmcnt(4) (leaves exactly B(u+2) in flight) | barrier.
// Safety proofs: A(u+1) parity != A(u) parity; tile u-1's A-reads drain
// (per-wave lgkm(0)) before barrier(u) < stageA issue. B slots u, u+1, u+2
// pairwise distinct mod 3 -> stageB never overlaps any live B reads; slot
// (u+2)%3's last readers (tile u-1) drained before barrier(u). vmcnt(4) +
// barrier makes "every wave retired A(u+1),B(u+1)" collective.
// Waves are NOT phase-locked between barriers -> one wave's reads hide under
// the other's MFMA backlog; barrier is crossed while MFMAs still execute.
// Read/swizzle pattern byte-identical to round 4 (measured 0 conflicts):
// granule = (hi ^ (fr&7)) ^ 4*ks; DMA source pre-swizzled q=(tid&7)^((tid>>3)&7).
__global__ __launch_bounds__(512, 2) void gemm_kernel(
    const u16* __restrict__ Xb, const u16* __restrict__ Wt,
    const float* __restrict__ bias, float* __restrict__ C) {
    extern __shared__ __align__(16) u16 lds[];   // 81920 elems = 160 KiB

    const int tid = threadIdx.x;
    const int l  = tid & 63;
    const int w  = tid >> 6;          // wave 0..7
    const int wm = w >> 2;            // 0..1
    const int wn = w & 3;             // 0..3

    // T1: XCD-bijective swizzle (512 blocks, 512 % 8 == 0)
    const int swz = (blockIdx.x & 7) * 64 + (blockIdx.x >> 3);
    const int m0 = (swz >> 4) * 256;  // 32 M-tiles
    const int n0 = (swz & 15) * 256;  // 16 N-tiles

    const u16* Ab = Xb + (size_t)m0 * K_DIM;
    const u16* Bb = Wt + (size_t)n0 * K_DIM;

    // staging: srow = tid>>3 (0..63), LDS granule tid&7 (linear dest)
    const int srow = tid >> 3;
    const int sq   = ((tid & 7) ^ (srow & 7)) * 8;    // pre-swizzled col elems

    // reads: fr = row-within-16, hi = k-granule quarter
    const int fr = l & 15, hi = l >> 4;
    const int g0 = (hi ^ (fr & 7)) << 3;              // ks0 col elems; ks1: ^32

    auto stageA = [&](int u, int h) {
#pragma unroll
        for (int s = 0; s < 2; ++s) {
            const u16* g = Ab + (size_t)(h * 128 + s * 64 + srow) * K_DIM + u * 64 + sq;
            gload_lds16(g, &lds[(u & 1) * 16384 + h * 8192 + s * 4096 + tid * 8]);
        }
    };
    auto stageB = [&](int u, int slot, int h) {
#pragma unroll
        for (int s = 0; s < 2; ++s) {
            const u16* g = Bb + (size_t)(h * 128 + s * 64 + srow) * K_DIM + u * 64 + sq;
            gload_lds16(g, &lds[32768 + slot * 16384 + h * 8192 + s * 4096 + tid * 8]);
        }
    };

    f32x4 acc[8][4] = {};

    // ---- prologue: A(0), B(0)->slot0, B(1)->slot1; wait A(0),B(0) ----
    stageA(0, 0); stageA(0, 1);
    stageB(0, 0, 0); stageB(0, 0, 1);
    stageB(1, 1, 0); stageB(1, 1, 1);
    asm volatile("s_waitcnt vmcnt(4)" ::: "memory");
    __builtin_amdgcn_sched_barrier(0);
    __builtin_amdgcn_s_barrier();

#define MFMA32()                                                              \
    _Pragma("unroll") for (int mb = 0; mb < 8; ++mb)                          \
    _Pragma("unroll") for (int nb = 0; nb < 4; ++nb)                          \
        acc[mb][nb] = __builtin_amdgcn_mfma_f32_16x16x32_bf16(                \
            a[mb], b[nb], acc[mb][nb], 0, 0, 0);

    int scur = 0, snxt = 2;   // B slot of tile u; slot for B(u+2)
    for (int u = 0; u < NTK; ++u) {
        const int ab = (u & 1) * 16384 + (wm * 128 + fr) * 64;
        const int bb = 32768 + scur * 16384 + (wn * 64 + fr) * 64;
        bf16x8 a[8], b[4];

        // ======== phase ks0 ========
#pragma unroll
        for (int nb = 0; nb < 4; ++nb)
            b[nb] = *(const bf16x8*)&lds[bb + nb * 1024 + g0];
#pragma unroll
        for (int mb = 0; mb < 8; ++mb)
            a[mb] = *(const bf16x8*)&lds[ab + mb * 1024 + g0];
        if (u + 1 < NTK) { stageA(u + 1, 0); stageA(u + 1, 1); }
        asm volatile("s_waitcnt lgkmcnt(0)" ::: "memory");
        __builtin_amdgcn_sched_barrier(0);
        __builtin_amdgcn_s_setprio(1);
        MFMA32();
        __builtin_amdgcn_s_setprio(0);

        // ======== phase ks1 ========
#pragma unroll
        for (int nb = 0; nb < 4; ++nb)
            b[nb] = *(const bf16x8*)&lds[bb + nb * 1024 + (g0 ^ 32)];
#pragma unroll
        for (int mb = 0; mb < 8; ++mb)
            a[mb] = *(const bf16x8*)&lds[ab + mb * 1024 + (g0 ^ 32)];
        if (u + 2 < NTK) { stageB(u + 2, snxt, 0); stageB(u + 2, snxt, 1); }
        asm volatile("s_waitcnt lgkmcnt(0)" ::: "memory");
        __builtin_amdgcn_sched_barrier(0);
        __builtin_amdgcn_s_setprio(1);
        MFMA32();
        __builtin_amdgcn_s_setprio(0);

        // counted drain: leave exactly B(u+2) (newest 4 DMAs) in flight
        if (u + 2 < NTK) {
            asm volatile("s_waitcnt vmcnt(4)" ::: "memory");
        } else if (u + 1 < NTK) {
            asm volatile("s_waitcnt vmcnt(0)" ::: "memory");
        }
        __builtin_amdgcn_sched_barrier(0);
        __builtin_amdgcn_s_barrier();

        scur = (scur == 2) ? 0 : scur + 1;
        snxt = (snxt == 2) ? 0 : snxt + 1;
    }
#undef MFMA32

    // ---- epilogue: C/D layout col=lane&15, row=(lane>>4)*4+reg (verified r4) ----
    const int orow0 = m0 + wm * 128;
    const int ocol0 = n0 + wn * 64;
    float bv[4];
#pragma unroll
    for (int nb = 0; nb < 4; ++nb) bv[nb] = bias[ocol0 + nb * 16 + fr];
#pragma unroll
    for (int mb = 0; mb < 8; ++mb)
#pragma unroll
        for (int nb = 0; nb < 4; ++nb)
#pragma unroll
            for (int j = 0; j < 4; ++j)
                C[(size_t)(orow0 + mb * 16 + hi * 4 + j) * N_DIM
                  + ocol0 + nb * 16 + fr] = acc[mb][nb][j] + bv[nb];
}

extern "C" void kernel_launch(void* const* d_in, const int* in_sizes, int n_in,
                              void* d_out, int out_size, void* d_ws, size_t ws_size,
                              hipStream_t stream) {
    const float* x     = (const float*)d_in[0];
    const float* w_loc = (const float*)d_in[1];
    const float* w_std = (const float*)d_in[2];
    const float* b_loc = (const float*)d_in[3];
    const float* b_std = (const float*)d_in[4];
    const float* eps_w = (const float*)d_in[5];
    const float* eps_b = (const float*)d_in[6];
    float* out = (float*)d_out;

    char* ws = (char*)d_ws;
    u16* Xb   = (u16*)ws;                                            // 64 MB
    u16* Wt   = (u16*)(ws + (size_t)M_DIM * K_DIM * 2);              // 32 MB
    float* bv = (float*)(ws + (size_t)M_DIM * K_DIM * 2
                            + (size_t)N_DIM * K_DIM * 2);            // 16 KB

    (void)hipFuncSetAttribute((const void*)gemm_kernel,
                              hipFuncAttributeMaxDynamicSharedMemorySize, 163840);

    conv_x_kernel<<<2048, 256, 0, stream>>>(x, Xb, (long long)M_DIM * K_DIM / 8);
    wconv_kernel<<<(K_DIM / 64) * (N_DIM / 64), 256, 0, stream>>>(w_loc, w_std, eps_w, Wt);
    bias_kernel<<<N_DIM / 256, 256, 0, stream>>>(b_loc, b_std, eps_b, bv);
    gemm_kernel<<<(M_DIM / 256) * (N_DIM / 256), 512, 163840, stream>>>(Xb, Wt, bv, out);
}